// Round 1
// 390.845 us; speedup vs baseline: 1.0152x; 1.0152x over previous
//
#include <hip/hip_runtime.h>
#include <hip/hip_bf16.h>

#define NEG_SLOPE 0.2f
#define LOG2E 1.4426950408889634f
// s_getreg imm: (size-1)<<11 | offset<<6 | id ; HW_REG_XCC_ID = 20 (CDNA3/4)
#define HWREG_XCC_ID_FULL (((32 - 1) << 11) | (0 << 6) | 20)

typedef _Float16 f16;
typedef f16 f16x8 __attribute__((ext_vector_type(8)));
typedef float f32x4 __attribute__((ext_vector_type(4)));

__device__ __forceinline__ float lrelu(float v) { return v > 0.f ? v : NEG_SLOPE * v; }

__device__ __forceinline__ unsigned pack_h2(float a, float b) {
    union { f16 h[2]; unsigned u; } c;
    c.h[0] = (f16)a; c.h[1] = (f16)b;
    return c.u;
}
__device__ __forceinline__ float2 unpack_h2(unsigned u) {
    union { unsigned u; f16 h[2]; } c;
    c.u = u;
    return make_float2((float)c.h[0], (float)c.h[1]);
}

// Detect whether edge_index arrived as int64 (odd 32-bit words all zero) or int32.
__global__ void k_detect(const int* __restrict__ ei32, int npairs, int* flag) {
    __shared__ int found;
    if (threadIdx.x == 0) found = 0;
    __syncthreads();
    for (int i = threadIdx.x; i < npairs; i += blockDim.x) {
        if (ei32[2 * i + 1] != 0) found = 1;
    }
    __syncthreads();
    if (threadIdx.x == 0) *flag = found ? 0 : 1;   // 1 => int64
}

__device__ __forceinline__ void load_edge(const void* ei, int f64, int e, int E, int& s, int& d) {
    if (f64) {
        const long long* p = (const long long*)ei;
        s = (int)p[e];
        d = (int)p[(long long)E + e];
    } else {
        const int* p = (const int*)ei;
        s = p[e];
        d = p[E + e];
    }
}

// ---------------- CSR build (XCD-sharded histogram) ----------------
__global__ void k_degree(const void* __restrict__ ei, const int* __restrict__ flag,
                         int* __restrict__ deg_part, int* __restrict__ rank, int N, int E) {
    int e = blockIdx.x * blockDim.x + threadIdx.x;
    if (e >= E) return;
    int s, d;
    load_edge(ei, *flag, e, E, s, d);
    int xcc = (int)(__builtin_amdgcn_s_getreg(HWREG_XCC_ID_FULL) & 7u);
    int lr = atomicAdd(&deg_part[xcc * N + d], 1);
    rank[e] = (xcc << 24) | lr;
}

__global__ void k_sumdeg(int* __restrict__ deg_part, int* __restrict__ deg, int N) {
    int d = blockIdx.x * blockDim.x + threadIdx.x;
    if (d >= N) return;
    int p = 0;
#pragma unroll
    for (int x = 0; x < 8; x++) {
        int t = deg_part[x * N + d];
        deg_part[x * N + d] = p;
        p += t;
    }
    deg[d] = p;
}

__global__ __launch_bounds__(1024) void k_scan_blk(const int* __restrict__ deg,
                                                   int* __restrict__ offsets,
                                                   int* __restrict__ blksum, int N) {
    __shared__ int wsums[16];
    const int t = threadIdx.x;
    const int lane = t & 63;
    const int wid = t >> 6;
    int idx = blockIdx.x * 4096 + t * 4;
    int v0 = (idx + 0 < N) ? deg[idx + 0] : 0;
    int v1 = (idx + 1 < N) ? deg[idx + 1] : 0;
    int v2 = (idx + 2 < N) ? deg[idx + 2] : 0;
    int v3 = (idx + 3 < N) ? deg[idx + 3] : 0;
    int s1 = v0 + v1, s2 = s1 + v2, s3 = s2 + v3;
    int inc = s3;
#pragma unroll
    for (int off = 1; off < 64; off <<= 1) {
        int y = __shfl_up(inc, off);
        if (lane >= off) inc += y;
    }
    if (lane == 63) wsums[wid] = inc;
    __syncthreads();
    if (wid == 0) {
        int v = (lane < 16) ? wsums[lane] : 0;
        int wi = v;
#pragma unroll
        for (int off = 1; off < 16; off <<= 1) {
            int y = __shfl_up(wi, off);
            if (lane >= off) wi += y;
        }
        if (lane < 16) wsums[lane] = wi - v;
        if (lane == 15) blksum[blockIdx.x] = wi;
    }
    __syncthreads();
    int excl = wsums[wid] + (inc - s3);
    if (idx + 0 < N) offsets[idx + 1] = excl + v0;
    if (idx + 1 < N) offsets[idx + 2] = excl + s1;
    if (idx + 2 < N) offsets[idx + 3] = excl + s2;
    if (idx + 3 < N) offsets[idx + 4] = excl + s3;
}

__global__ void k_scan_top(const int* __restrict__ blksum, int* __restrict__ blkoff, int G) {
    int l = threadIdx.x;
    int v = (l < G) ? blksum[l] : 0;
    int inc = v;
#pragma unroll
    for (int off = 1; off < 64; off <<= 1) {
        int y = __shfl_up(inc, off);
        if (l >= off) inc += y;
    }
    if (l < G) blkoff[l] = inc - v;
}

__global__ void k_scan_add(int* __restrict__ offsets, const int* __restrict__ blkoff, int N) {
    int n = blockIdx.x * blockDim.x + threadIdx.x;
    if (n >= N) return;
    offsets[n + 1] += blkoff[n >> 12];
    if (n == 0) offsets[0] = 0;
}

__global__ void k_scatter(const void* __restrict__ ei, const int* __restrict__ flag,
                          const int* __restrict__ offsets, const int* __restrict__ deg_part,
                          const int* __restrict__ rank, int* __restrict__ csr_src,
                          int N, int E) {
    int e = blockIdx.x * blockDim.x + threadIdx.x;
    if (e >= E) return;
    int s, d;
    load_edge(ei, *flag, e, E, s, d);
    int r = rank[e];
    int xcc = r >> 24;
    int lr = r & 0xFFFFFF;
    csr_src[offsets[d] + deg_part[xcc * N + d] + lr] = s;
}

// ---------------- weight prep: transposed f16 copies ----------------
__global__ void k_prep(const float* __restrict__ W1, const float* __restrict__ W2,
                       f16* __restrict__ W1t, f16* __restrict__ W2t) {
    int o = blockIdx.x * 256 + threadIdx.x;
    if (o < 128 * 128) {
        int n = o >> 7, k = o & 127;
        W1t[o] = (f16)W1[k * 128 + n];
    } else {
        int o2 = o - 128 * 128;
        if (o2 < 48 * 128) {
            int n = o2 >> 7, k = o2 & 127;
            W2t[o2] = (f16)(n < 40 ? W2[k * 40 + n] : 0.f);
        }
    }
}

// ---------------- GEMM1 (MFMA f16): Af = (f16)(X @ W1), [N][128] ----------------
__global__ __launch_bounds__(256) void k_gemm1(const float* __restrict__ X,
                                               const f16* __restrict__ W1t,
                                               f16* __restrict__ Af, int N) {
    __shared__ f16 sA[64 * 136];
    __shared__ f16 sB[128 * 136];
    const int t = threadIdx.x;
    const int row0 = blockIdx.x * 64;

    {
        int r = t >> 2, seg = t & 3;
        int row = row0 + r;
        if (row >= N) row = N - 1;
        const float4* xg = (const float4*)(X + (size_t)row * 128 + seg * 32);
        unsigned tmp[16];
#pragma unroll
        for (int j = 0; j < 8; j++) {
            float4 v = xg[j];
            tmp[2 * j]     = pack_h2(v.x, v.y);
            tmp[2 * j + 1] = pack_h2(v.z, v.w);
        }
        uint4* dst = (uint4*)&sA[r * 136 + seg * 32];
#pragma unroll
        for (int j = 0; j < 4; j++) dst[j] = ((uint4*)tmp)[j];
        int n = t >> 1, half = (t & 1) * 64;
        const uint4* src = (const uint4*)(W1t + n * 128 + half);
        uint4* dw = (uint4*)&sB[n * 136 + half];
#pragma unroll
        for (int j = 0; j < 8; j++) dw[j] = src[j];
    }
    __syncthreads();

    const int w = t >> 6, lane = t & 63, ln = lane & 15, q = lane >> 4;
    f32x4 acc[8];
#pragma unroll
    for (int c = 0; c < 8; c++) acc[c] = (f32x4){0.f, 0.f, 0.f, 0.f};

#pragma unroll
    for (int ks = 0; ks < 4; ks++) {
        f16x8 a = *(const f16x8*)&sA[(w * 16 + ln) * 136 + ks * 32 + q * 8];
#pragma unroll
        for (int c = 0; c < 8; c++) {
            f16x8 b = *(const f16x8*)&sB[(c * 16 + ln) * 136 + ks * 32 + q * 8];
            acc[c] = __builtin_amdgcn_mfma_f32_16x16x32_f16(a, b, acc[c], 0, 0, 0);
        }
    }

#pragma unroll
    for (int c = 0; c < 8; c++)
#pragma unroll
        for (int reg = 0; reg < 4; reg++) {
            int rg = row0 + w * 16 + q * 4 + reg;
            if (rg < N) Af[(size_t)rg * 128 + c * 16 + ln] = (f16)acc[c][reg];
        }
}

// ---------------- GEMM2 (MFMA f16): X2f = (f16)(Hf @ W2), [N][40] ----------------
__global__ __launch_bounds__(256) void k_gemm2(const f16* __restrict__ Hf,
                                               const f16* __restrict__ W2t,
                                               f16* __restrict__ X2f, int N) {
    __shared__ f16 sA[64 * 136];
    __shared__ f16 sB[48 * 136];
    const int t = threadIdx.x;
    const int row0 = blockIdx.x * 64;
    {
        int r = t >> 2, seg = t & 3;
        int row = row0 + r;
        if (row >= N) row = N - 1;
        const uint4* hg = (const uint4*)(Hf + (size_t)row * 128 + seg * 32);
        uint4* dst = (uint4*)&sA[r * 136 + seg * 32];
#pragma unroll
        for (int j = 0; j < 4; j++) dst[j] = hg[j];
        const uint4* wsrc = (const uint4*)W2t;
#pragma unroll
        for (int u = t; u < 768; u += 256) {
            int o = u * 8;
            int n = o >> 7, ko = o & 127;
            *(uint4*)&sB[n * 136 + ko] = wsrc[u];
        }
    }
    __syncthreads();

    const int w = t >> 6, lane = t & 63, ln = lane & 15, q = lane >> 4;
    f32x4 acc[3];
#pragma unroll
    for (int c = 0; c < 3; c++) acc[c] = (f32x4){0.f, 0.f, 0.f, 0.f};

#pragma unroll
    for (int ks = 0; ks < 4; ks++) {
        f16x8 a = *(const f16x8*)&sA[(w * 16 + ln) * 136 + ks * 32 + q * 8];
#pragma unroll
        for (int c = 0; c < 3; c++) {
            f16x8 b = *(const f16x8*)&sB[(c * 16 + ln) * 136 + ks * 32 + q * 8];
            acc[c] = __builtin_amdgcn_mfma_f32_16x16x32_f16(a, b, acc[c], 0, 0, 0);
        }
    }

#pragma unroll
    for (int c = 0; c < 3; c++) {
        int col = c * 16 + ln;
        if (col < 40) {
#pragma unroll
            for (int reg = 0; reg < 4; reg++) {
                int rg = row0 + w * 16 + q * 4 + reg;
                if (rg < N) X2f[(size_t)rg * 40 + col] = (f16)acc[c][reg];
            }
        }
    }
}

// ---------------- attention dots (from f16), PRE-SCALED by log2(e) ----------------
// msg kernels then compute exp(lrelu(x)) as exp2(max(x', 0.2*x')) with x' = x*log2e
// (lrelu is positively homogeneous, so lrelu(c*x) = c*lrelu(x) for c>0).
__global__ void k_attn1(const f16* __restrict__ Af, const float* __restrict__ att_s,
                        const float* __restrict__ att_d, float* __restrict__ aS,
                        float* __restrict__ aD, int N) {
    int t = blockIdx.x * blockDim.x + threadIdx.x;
    if (t >= N * 4) return;
    int n = t >> 2, h = t & 3;
    const uint4* xr = (const uint4*)(Af + (size_t)n * 128 + h * 32);
    float ss = 0.f, sd = 0.f;
#pragma unroll
    for (int j = 0; j < 4; j++) {
        uint4 p = xr[j];
        float2 a0 = unpack_h2(p.x), a1 = unpack_h2(p.y), a2 = unpack_h2(p.z), a3 = unpack_h2(p.w);
        float xv[8] = {a0.x, a0.y, a1.x, a1.y, a2.x, a2.y, a3.x, a3.y};
        const float* as_ = att_s + h * 32 + j * 8;
        const float* ad_ = att_d + h * 32 + j * 8;
#pragma unroll
        for (int qq = 0; qq < 8; qq++) {
            ss += xv[qq] * as_[qq];
            sd += xv[qq] * ad_[qq];
        }
    }
    aS[t] = ss * LOG2E;
    aD[t] = sd * LOG2E;
}

__global__ void k_attn2(const f16* __restrict__ X2f, const float* __restrict__ att_s,
                        const float* __restrict__ att_d, float* __restrict__ aS,
                        float* __restrict__ aD, int N) {
    int n = blockIdx.x * blockDim.x + threadIdx.x;
    if (n >= N) return;
    const unsigned* xr = (const unsigned*)(X2f + (size_t)n * 40);
    float ss = 0.f, sd = 0.f;
#pragma unroll
    for (int j = 0; j < 20; j++) {
        float2 v = unpack_h2(xr[j]);
        ss += v.x * att_s[2 * j] + v.y * att_s[2 * j + 1];
        sd += v.x * att_d[2 * j] + v.y * att_d[2 * j + 1];
    }
    aS[n] = ss * LOG2E;
    aD[n] = sd * LOG2E;
}

// ---------------- fused message + online softmax denominator, layer 1 ----------------
// 1 node/wave. 4 edge-slots of 16 lanes; each lane covers 8 channels (dwordx4
// gather = exactly one 256 B Af row per slot). Neighbor ids for the first 64
// edges are bulk-loaded into one VGPR/lane and served with ds_bpermute (no
// per-edge csr load chain). Invalid slots clamp to row 0 (hot line) with w=0.
// Final: 4-group reduction via shfl_xor(16/32), group 0 stores 16 B/lane.
__global__ __launch_bounds__(256) void k_msg1(const int* __restrict__ offsets,
                                              const int* __restrict__ csr_src,
                                              const float* __restrict__ aS,
                                              const float* __restrict__ aD,
                                              const f16* __restrict__ Af,
                                              const float* __restrict__ b1,
                                              f16* __restrict__ Hf, int N) {
    const int lane = threadIdx.x & 63;
    const int n = blockIdx.x * 4 + (threadIdx.x >> 6);
    const bool node_ok = (n < N);
    const int g = lane >> 4;        // edge slot 0..3
    const int p = lane & 15;        // channel group: ch = p*8 .. p*8+7
    const int h = p >> 2;           // head 0..3

    int b = 0, e = 0;
    float adh = 0.f;
    if (node_ok) {
        b = offsets[n];
        e = offsets[n + 1];
        adh = aD[n * 4 + h];
    }

    float acc[8];
#pragma unroll
    for (int k = 0; k < 8; k++) acc[k] = 0.f;
    float wsum = 0.f;

    // self edge: all lanes load row n (broadcast); only slot 0 contributes.
    if (node_ok) {
        float xs = aS[n * 4 + h] + adh;
        float ws = __builtin_amdgcn_exp2f(fmaxf(xs, NEG_SLOPE * xs));
        if (g != 0) ws = 0.f;
        const f16x8 hv = *(const f16x8*)(Af + (size_t)n * 128 + p * 8);
#pragma unroll
        for (int k = 0; k < 8; k++) acc[k] = fmaf(ws, (float)hv[k], acc[k]);
        wsum = ws;
    }

    // preload up to 64 neighbor ids (one per lane)
    int sreg = 0;
    if (node_ok && e > b) {
        int idx = b + lane;
        if (idx >= e) idx = e - 1;
        sreg = csr_src[idx];
    }

    int i = b;
    // main loop: first 64 edges served from registers via bpermute
#pragma unroll 2
    for (; i < e && (i - b) + 4 <= 64; i += 4) {
        int j = i + g;
        bool valid = (j < e);
        int s = __builtin_amdgcn_ds_bpermute((j - b) << 2, sreg);
        if (!valid) s = 0;                               // hot row 0, w=0
        float sv = aS[s * 4 + h];
        const f16x8 hv = *(const f16x8*)(Af + (size_t)s * 128 + p * 8);
        float x = sv + adh;
        float wgt = __builtin_amdgcn_exp2f(fmaxf(x, NEG_SLOPE * x));
        if (!valid) wgt = 0.f;
#pragma unroll
        for (int k = 0; k < 8; k++) acc[k] = fmaf(wgt, (float)hv[k], acc[k]);
        wsum += wgt;
    }
    // residual (deg > 64): direct csr loads
    for (; i < e; i += 4) {
        int j = i + g;
        bool valid = (j < e);
        int jc = valid ? j : (e - 1);
        int s = csr_src[jc];
        if (!valid) s = 0;
        float sv = aS[s * 4 + h];
        const f16x8 hv = *(const f16x8*)(Af + (size_t)s * 128 + p * 8);
        float x = sv + adh;
        float wgt = __builtin_amdgcn_exp2f(fmaxf(x, NEG_SLOPE * x));
        if (!valid) wgt = 0.f;
#pragma unroll
        for (int k = 0; k < 8; k++) acc[k] = fmaf(wgt, (float)hv[k], acc[k]);
        wsum += wgt;
    }

    // reduce across the 4 edge slots (stride-16 lanes)
#pragma unroll
    for (int k = 0; k < 8; k++) {
        acc[k] += __shfl_xor(acc[k], 16);
        acc[k] += __shfl_xor(acc[k], 32);
    }
    wsum += __shfl_xor(wsum, 16);
    wsum += __shfl_xor(wsum, 32);

    if (node_ok && g == 0) {
        float inv = __builtin_amdgcn_rcpf(wsum);
        const float4* bb = (const float4*)(b1 + p * 8);
        float4 b0 = bb[0], b4 = bb[1];
        float bv[8] = {b0.x, b0.y, b0.z, b0.w, b4.x, b4.y, b4.z, b4.w};
        union { f16 h8[8]; uint4 u; } o;
#pragma unroll
        for (int k = 0; k < 8; k++) {
            float v = fmaf(acc[k], inv, bv[k]);
            o.h8[k] = (f16)fmaxf(v, 0.f);
        }
        *(uint4*)(Hf + (size_t)n * 128 + p * 8) = o.u;
    }
}

// ---------------- fused message + softmax denominator, layer 2 ----------------
// 1 node/wave (removes the old 3-nodes/wave degree-imbalance divergence).
// 12 edge-slots of 5 lanes; each lane covers 8 of 40 channels (dwordx4 = one
// 80 B X2f row per slot). Non-pow2 slot reduction via small LDS epilogue.
// No early returns (the __syncthreads must be reached by all threads).
__global__ __launch_bounds__(256) void k_msg2(const int* __restrict__ offsets,
                                              const int* __restrict__ csr_src,
                                              const float* __restrict__ aS,
                                              const float* __restrict__ aD,
                                              const f16* __restrict__ X2f,
                                              const float* __restrict__ b2,
                                              float* __restrict__ OUT, int N) {
    __shared__ float red[4][60][9];
    const int lane = threadIdx.x & 63;
    const int wv = threadIdx.x >> 6;
    const int n = blockIdx.x * 4 + wv;
    const bool node_ok = (n < N);
    const int g = lane / 5;          // edge slot 0..11 (lanes 60-63 -> 12, inactive)
    const int p = lane % 5;          // channel group: ch = p*8 .. p*8+7
    const bool lane_ok = (g < 12);

    int b = 0, e = 0;
    float adh = 0.f;
    if (node_ok) {
        b = offsets[n];
        e = offsets[n + 1];
        adh = aD[n];
    }

    float acc[8];
#pragma unroll
    for (int k = 0; k < 8; k++) acc[k] = 0.f;
    float wsum = 0.f;

    // self edge (slot 0 contributes)
    if (node_ok) {
        float xs = aS[n] + adh;
        float ws = __builtin_amdgcn_exp2f(fmaxf(xs, NEG_SLOPE * xs));
        if (!(lane_ok && g == 0)) ws = 0.f;
        const f16x8 hv = *(const f16x8*)(X2f + (size_t)n * 40 + p * 8);
#pragma unroll
        for (int k = 0; k < 8; k++) acc[k] = fmaf(ws, (float)hv[k], acc[k]);
        wsum = ws;
    }

    int sreg = 0;
    if (node_ok && e > b) {
        int idx = b + lane;
        if (idx >= e) idx = e - 1;
        sreg = csr_src[idx];
    }

    int i = b;
    for (; i < e && (i - b) + 12 <= 64; i += 12) {
        int j = i + g;
        bool valid = lane_ok && (j < e);
        int s = __builtin_amdgcn_ds_bpermute(((j - b) & 63) << 2, sreg);
        if (!valid) s = 0;
        float sv = aS[s];
        const f16x8 hv = *(const f16x8*)(X2f + (size_t)s * 40 + p * 8);
        float x = sv + adh;
        float wgt = __builtin_amdgcn_exp2f(fmaxf(x, NEG_SLOPE * x));
        if (!valid) wgt = 0.f;
#pragma unroll
        for (int k = 0; k < 8; k++) acc[k] = fmaf(wgt, (float)hv[k], acc[k]);
        wsum += wgt;
    }
    for (; i < e; i += 12) {
        int j = i + g;
        bool valid = lane_ok && (j < e);
        int jc = (j < e) ? j : (e - 1);
        int s = csr_src[jc];
        if (!valid) s = 0;
        float sv = aS[s];
        const f16x8 hv = *(const f16x8*)(X2f + (size_t)s * 40 + p * 8);
        float x = sv + adh;
        float wgt = __builtin_amdgcn_exp2f(fmaxf(x, NEG_SLOPE * x));
        if (!valid) wgt = 0.f;
#pragma unroll
        for (int k = 0; k < 8; k++) acc[k] = fmaf(wgt, (float)hv[k], acc[k]);
        wsum += wgt;
    }

    if (lane_ok) {
#pragma unroll
        for (int k = 0; k < 8; k++) red[wv][lane][k] = acc[k];
        red[wv][lane][8] = wsum;
    }
    __syncthreads();

    if (node_ok && lane < 40) {
        int pp = lane >> 3, kk = lane & 7;
        float s_ = 0.f, ws_ = 0.f;
#pragma unroll
        for (int gg = 0; gg < 12; gg++) {
            s_  += red[wv][gg * 5 + pp][kk];
            ws_ += red[wv][gg * 5][8];
        }
        float inv = __builtin_amdgcn_rcpf(ws_);
        OUT[(size_t)n * 40 + lane] = fmaf(s_, inv, b2[lane]);
    }
}

extern "C" void kernel_launch(void* const* d_in, const int* in_sizes, int n_in,
                              void* d_out, int out_size, void* d_ws, size_t ws_size,
                              hipStream_t stream) {
    const float* x   = (const float*)d_in[0];
    const void*  ei  = d_in[1];
    const float* W1  = (const float*)d_in[2];
    const float* as1 = (const float*)d_in[3];
    const float* ad1 = (const float*)d_in[4];
    const float* b1  = (const float*)d_in[5];
    const float* W2  = (const float*)d_in[6];
    const float* as2 = (const float*)d_in[7];
    const float* ad2 = (const float*)d_in[8];
    const float* b2  = (const float*)d_in[9];
    float* out = (float*)d_out;

    const int N = in_sizes[0] / 128;
    const int E = in_sizes[1] / 2;

    // workspace layout — all 16B-aligned
    char* w = (char*)d_ws;
    auto alloc = [&](size_t bytes) {
        char* p = w;
        w += (bytes + 15) & ~(size_t)15;
        return p;
    };
    int* flag      = (int*)alloc(16);
    int* offsets   = (int*)alloc((size_t)(N + 1) * 4);
    int* deg       = (int*)alloc((size_t)N * 4);
    int* deg_part  = (int*)alloc((size_t)N * 8 * 4);   // [8][N] sharded histogram
    int* rank      = (int*)alloc((size_t)E * 4);
    int* csr_src   = (int*)alloc((size_t)E * 4);
    int* blksum    = (int*)alloc(64 * 4);
    int* blkoff    = (int*)alloc(64 * 4);
    float* aS1     = (float*)alloc((size_t)N * 4 * 4);
    float* aD1     = (float*)alloc((size_t)N * 4 * 4);
    float* aS2     = (float*)alloc((size_t)N * 4);
    float* aD2     = (float*)alloc((size_t)N * 4);
    f16* W1t       = (f16*)alloc(128 * 128 * 2);
    f16* W2t       = (f16*)alloc(48 * 128 * 2);
    f16* Af        = (f16*)alloc((size_t)N * 128 * 2);
    f16* X2f       = (f16*)alloc((size_t)N * 40 * 2);
    f16* Hf        = (f16*)alloc((size_t)N * 128 * 2);

    k_detect<<<1, 256, 0, stream>>>((const int*)ei, 1024, flag);
    k_prep<<<88, 256, 0, stream>>>(W1, W2, W1t, W2t);

    // CSR build (XCD-sharded; shared by both layers)
    hipMemsetAsync(deg_part, 0, (size_t)N * 8 * 4, stream);
    k_degree<<<(E + 255) / 256, 256, 0, stream>>>(ei, flag, deg_part, rank, N, E);
    k_sumdeg<<<(N + 255) / 256, 256, 0, stream>>>(deg_part, deg, N);
    const int G = (N + 4095) / 4096;
    k_scan_blk<<<G, 1024, 0, stream>>>(deg, offsets, blksum, N);
    k_scan_top<<<1, 64, 0, stream>>>(blksum, blkoff, G);
    k_scan_add<<<(N + 255) / 256, 256, 0, stream>>>(offsets, blkoff, N);
    k_scatter<<<(E + 255) / 256, 256, 0, stream>>>(ei, flag, offsets, deg_part, rank,
                                                   csr_src, N, E);

    // layer 1
    const int gb = (N + 63) / 64;
    k_gemm1<<<gb, 256, 0, stream>>>(x, W1t, Af, N);
    k_attn1<<<(N * 4 + 255) / 256, 256, 0, stream>>>(Af, as1, ad1, aS1, aD1, N);
    k_msg1<<<(N + 3) / 4, 256, 0, stream>>>(offsets, csr_src, aS1, aD1, Af, b1, Hf, N);

    // layer 2
    k_gemm2<<<gb, 256, 0, stream>>>(Hf, W2t, X2f, N);
    k_attn2<<<(N + 255) / 256, 256, 0, stream>>>(X2f, as2, ad2, aS2, aD2, N);
    k_msg2<<<(N + 3) / 4, 256, 0, stream>>>(offsets, csr_src, aS2, aD2, X2f, b2, out, N);
}

// Round 2
// 388.274 us; speedup vs baseline: 1.0219x; 1.0066x over previous
//
#include <hip/hip_runtime.h>
#include <hip/hip_bf16.h>

#define NEG_SLOPE 0.2f
#define LOG2E 1.4426950408889634f
// s_getreg imm: (size-1)<<11 | offset<<6 | id ; HW_REG_XCC_ID = 20 (CDNA3/4)
#define HWREG_XCC_ID_FULL (((32 - 1) << 11) | (0 << 6) | 20)

typedef _Float16 f16;
typedef f16 f16x8 __attribute__((ext_vector_type(8)));
typedef float f32x4 __attribute__((ext_vector_type(4)));

__device__ __forceinline__ unsigned pack_h2(float a, float b) {
    union { f16 h[2]; unsigned u; } c;
    c.h[0] = (f16)a; c.h[1] = (f16)b;
    return c.u;
}

// Detect whether edge_index arrived as int64 (odd 32-bit words all zero) or int32.
__global__ void k_detect(const int* __restrict__ ei32, int npairs, int* flag) {
    __shared__ int found;
    if (threadIdx.x == 0) found = 0;
    __syncthreads();
    for (int i = threadIdx.x; i < npairs; i += blockDim.x) {
        if (ei32[2 * i + 1] != 0) found = 1;
    }
    __syncthreads();
    if (threadIdx.x == 0) *flag = found ? 0 : 1;   // 1 => int64
}

__device__ __forceinline__ void load_edge(const void* ei, int f64, int e, int E, int& s, int& d) {
    if (f64) {
        const long long* p = (const long long*)ei;
        s = (int)p[e];
        d = (int)p[(long long)E + e];
    } else {
        const int* p = (const int*)ei;
        s = p[e];
        d = p[E + e];
    }
}

// ---------------- CSR build (XCD-sharded histogram) ----------------
__global__ void k_degree(const void* __restrict__ ei, const int* __restrict__ flag,
                         int* __restrict__ deg_part, int* __restrict__ rank, int N, int E) {
    int e = blockIdx.x * blockDim.x + threadIdx.x;
    if (e >= E) return;
    int s, d;
    load_edge(ei, *flag, e, E, s, d);
    int xcc = (int)(__builtin_amdgcn_s_getreg(HWREG_XCC_ID_FULL) & 7u);
    int lr = atomicAdd(&deg_part[xcc * N + d], 1);
    rank[e] = (xcc << 24) | lr;
}

__global__ void k_sumdeg(int* __restrict__ deg_part, int* __restrict__ deg, int N) {
    int d = blockIdx.x * blockDim.x + threadIdx.x;
    if (d >= N) return;
    int p = 0;
#pragma unroll
    for (int x = 0; x < 8; x++) {
        int t = deg_part[x * N + d];
        deg_part[x * N + d] = p;
        p += t;
    }
    deg[d] = p;
}

__global__ __launch_bounds__(1024) void k_scan_blk(const int* __restrict__ deg,
                                                   int* __restrict__ offsets,
                                                   int* __restrict__ blksum, int N) {
    __shared__ int wsums[16];
    const int t = threadIdx.x;
    const int lane = t & 63;
    const int wid = t >> 6;
    int idx = blockIdx.x * 4096 + t * 4;
    int v0 = (idx + 0 < N) ? deg[idx + 0] : 0;
    int v1 = (idx + 1 < N) ? deg[idx + 1] : 0;
    int v2 = (idx + 2 < N) ? deg[idx + 2] : 0;
    int v3 = (idx + 3 < N) ? deg[idx + 3] : 0;
    int s1 = v0 + v1, s2 = s1 + v2, s3 = s2 + v3;
    int inc = s3;
#pragma unroll
    for (int off = 1; off < 64; off <<= 1) {
        int y = __shfl_up(inc, off);
        if (lane >= off) inc += y;
    }
    if (lane == 63) wsums[wid] = inc;
    __syncthreads();
    if (wid == 0) {
        int v = (lane < 16) ? wsums[lane] : 0;
        int wi = v;
#pragma unroll
        for (int off = 1; off < 16; off <<= 1) {
            int y = __shfl_up(wi, off);
            if (lane >= off) wi += y;
        }
        if (lane < 16) wsums[lane] = wi - v;
        if (lane == 15) blksum[blockIdx.x] = wi;
    }
    __syncthreads();
    int excl = wsums[wid] + (inc - s3);
    if (idx + 0 < N) offsets[idx + 1] = excl + v0;
    if (idx + 1 < N) offsets[idx + 2] = excl + s1;
    if (idx + 2 < N) offsets[idx + 3] = excl + s2;
    if (idx + 3 < N) offsets[idx + 4] = excl + s3;
}

__global__ void k_scan_top(const int* __restrict__ blksum, int* __restrict__ blkoff, int G) {
    int l = threadIdx.x;
    int v = (l < G) ? blksum[l] : 0;
    int inc = v;
#pragma unroll
    for (int off = 1; off < 64; off <<= 1) {
        int y = __shfl_up(inc, off);
        if (l >= off) inc += y;
    }
    if (l < G) blkoff[l] = inc - v;
}

__global__ void k_scan_add(int* __restrict__ offsets, const int* __restrict__ blkoff, int N) {
    int n = blockIdx.x * blockDim.x + threadIdx.x;
    if (n >= N) return;
    offsets[n + 1] += blkoff[n >> 12];
    if (n == 0) offsets[0] = 0;
}

__global__ void k_scatter(const void* __restrict__ ei, const int* __restrict__ flag,
                          const int* __restrict__ offsets, const int* __restrict__ deg_part,
                          const int* __restrict__ rank, int* __restrict__ csr_src,
                          int N, int E) {
    int e = blockIdx.x * blockDim.x + threadIdx.x;
    if (e >= E) return;
    int s, d;
    load_edge(ei, *flag, e, E, s, d);
    int r = rank[e];
    int xcc = r >> 24;
    int lr = r & 0xFFFFFF;
    csr_src[offsets[d] + deg_part[xcc * N + d] + lr] = s;
}

// ---------------- weight prep: transposed f16 copies ----------------
__global__ void k_prep(const float* __restrict__ W1, const float* __restrict__ W2,
                       f16* __restrict__ W1t, f16* __restrict__ W2t) {
    int o = blockIdx.x * 256 + threadIdx.x;
    if (o < 128 * 128) {
        int n = o >> 7, k = o & 127;
        W1t[o] = (f16)W1[k * 128 + n];
    } else {
        int o2 = o - 128 * 128;
        if (o2 < 48 * 128) {
            int n = o2 >> 7, k = o2 & 127;
            W2t[o2] = (f16)(n < 40 ? W2[k * 40 + n] : 0.f);
        }
    }
}

// ---------------- GEMM1 (MFMA f16) + fused attn1 dots ----------------
// Af = (f16)(X @ W1) [N][128]; aS1/aD1[n*4+h] = LOG2E * dot(xw[n,h,:], att[h,:])
__global__ __launch_bounds__(256) void k_gemm1(const float* __restrict__ X,
                                               const f16* __restrict__ W1t,
                                               const float* __restrict__ as1,
                                               const float* __restrict__ ad1,
                                               f16* __restrict__ Af,
                                               float* __restrict__ aS1,
                                               float* __restrict__ aD1, int N) {
    __shared__ f16 sA[64 * 136];
    __shared__ f16 sB[128 * 136];
    const int t = threadIdx.x;
    const int row0 = blockIdx.x * 64;

    {
        int r = t >> 2, seg = t & 3;
        int row = row0 + r;
        if (row >= N) row = N - 1;
        const float4* xg = (const float4*)(X + (size_t)row * 128 + seg * 32);
        unsigned tmp[16];
#pragma unroll
        for (int j = 0; j < 8; j++) {
            float4 v = xg[j];
            tmp[2 * j]     = pack_h2(v.x, v.y);
            tmp[2 * j + 1] = pack_h2(v.z, v.w);
        }
        uint4* dst = (uint4*)&sA[r * 136 + seg * 32];
#pragma unroll
        for (int j = 0; j < 4; j++) dst[j] = ((uint4*)tmp)[j];
        int n = t >> 1, half = (t & 1) * 64;
        const uint4* src = (const uint4*)(W1t + n * 128 + half);
        uint4* dw = (uint4*)&sB[n * 136 + half];
#pragma unroll
        for (int j = 0; j < 8; j++) dw[j] = src[j];
    }
    __syncthreads();

    const int w = t >> 6, lane = t & 63, ln = lane & 15, q = lane >> 4;
    f32x4 acc[8];
#pragma unroll
    for (int c = 0; c < 8; c++) acc[c] = (f32x4){0.f, 0.f, 0.f, 0.f};

#pragma unroll
    for (int ks = 0; ks < 4; ks++) {
        f16x8 a = *(const f16x8*)&sA[(w * 16 + ln) * 136 + ks * 32 + q * 8];
#pragma unroll
        for (int c = 0; c < 8; c++) {
            f16x8 b = *(const f16x8*)&sB[(c * 16 + ln) * 136 + ks * 32 + q * 8];
            acc[c] = __builtin_amdgcn_mfma_f32_16x16x32_f16(a, b, acc[c], 0, 0, 0);
        }
    }

    // store Af
#pragma unroll
    for (int c = 0; c < 8; c++)
#pragma unroll
        for (int reg = 0; reg < 4; reg++) {
            int rg = row0 + w * 16 + q * 4 + reg;
            if (rg < N) Af[(size_t)rg * 128 + c * 16 + ln] = (f16)acc[c][reg];
        }

    // fused attn dots: col = c*16+ln; head h covers cols 32h..32h+31 (c=2h,2h+1)
    float ps[4][4], pd[4][4];   // [h][reg]
#pragma unroll
    for (int h = 0; h < 4; h++) {
        float as_lo = as1[32 * h + ln], as_hi = as1[32 * h + 16 + ln];
        float ad_lo = ad1[32 * h + ln], ad_hi = ad1[32 * h + 16 + ln];
#pragma unroll
        for (int reg = 0; reg < 4; reg++) {
            ps[h][reg] = acc[2 * h][reg] * as_lo + acc[2 * h + 1][reg] * as_hi;
            pd[h][reg] = acc[2 * h][reg] * ad_lo + acc[2 * h + 1][reg] * ad_hi;
        }
    }
#pragma unroll
    for (int h = 0; h < 4; h++)
#pragma unroll
        for (int reg = 0; reg < 4; reg++)
#pragma unroll
            for (int off = 1; off < 16; off <<= 1) {
                ps[h][reg] += __shfl_xor(ps[h][reg], off);
                pd[h][reg] += __shfl_xor(pd[h][reg], off);
            }
#pragma unroll
    for (int h = 0; h < 4; h++) {
        if (ln == 2 * h) {
#pragma unroll
            for (int reg = 0; reg < 4; reg++) {
                int rg = row0 + w * 16 + q * 4 + reg;
                if (rg < N) aS1[rg * 4 + h] = ps[h][reg] * LOG2E;
            }
        }
        if (ln == 2 * h + 1) {
#pragma unroll
            for (int reg = 0; reg < 4; reg++) {
                int rg = row0 + w * 16 + q * 4 + reg;
                if (rg < N) aD1[rg * 4 + h] = pd[h][reg] * LOG2E;
            }
        }
    }
}

// ---------------- GEMM2 (MFMA f16) + fused attn2 dots ----------------
// X2f = (f16)(Hf @ W2) stored PADDED [N][64] (row = one aligned 128B line);
// aS2/aD2[n] = LOG2E * dot(x2[n,:40], att2)
__global__ __launch_bounds__(256) void k_gemm2(const f16* __restrict__ Hf,
                                               const f16* __restrict__ W2t,
                                               const float* __restrict__ as2,
                                               const float* __restrict__ ad2,
                                               f16* __restrict__ X2f,
                                               float* __restrict__ aS2,
                                               float* __restrict__ aD2, int N) {
    __shared__ f16 sA[64 * 136];
    __shared__ f16 sB[48 * 136];
    const int t = threadIdx.x;
    const int row0 = blockIdx.x * 64;
    {
        int r = t >> 2, seg = t & 3;
        int row = row0 + r;
        if (row >= N) row = N - 1;
        const uint4* hg = (const uint4*)(Hf + (size_t)row * 128 + seg * 32);
        uint4* dst = (uint4*)&sA[r * 136 + seg * 32];
#pragma unroll
        for (int j = 0; j < 4; j++) dst[j] = hg[j];
        const uint4* wsrc = (const uint4*)W2t;
#pragma unroll
        for (int u = t; u < 768; u += 256) {
            int o = u * 8;
            int n = o >> 7, ko = o & 127;
            *(uint4*)&sB[n * 136 + ko] = wsrc[u];
        }
    }
    __syncthreads();

    const int w = t >> 6, lane = t & 63, ln = lane & 15, q = lane >> 4;
    f32x4 acc[3];
#pragma unroll
    for (int c = 0; c < 3; c++) acc[c] = (f32x4){0.f, 0.f, 0.f, 0.f};

#pragma unroll
    for (int ks = 0; ks < 4; ks++) {
        f16x8 a = *(const f16x8*)&sA[(w * 16 + ln) * 136 + ks * 32 + q * 8];
#pragma unroll
        for (int c = 0; c < 3; c++) {
            f16x8 b = *(const f16x8*)&sB[(c * 16 + ln) * 136 + ks * 32 + q * 8];
            acc[c] = __builtin_amdgcn_mfma_f32_16x16x32_f16(a, b, acc[c], 0, 0, 0);
        }
    }

#pragma unroll
    for (int c = 0; c < 3; c++) {
        int col = c * 16 + ln;
        if (col < 40) {
#pragma unroll
            for (int reg = 0; reg < 4; reg++) {
                int rg = row0 + w * 16 + q * 4 + reg;
                if (rg < N) X2f[(size_t)rg * 64 + col] = (f16)acc[c][reg];
            }
        }
    }

    // fused attn dots
    float ps[4], pd[4];
#pragma unroll
    for (int reg = 0; reg < 4; reg++) { ps[reg] = 0.f; pd[reg] = 0.f; }
#pragma unroll
    for (int c = 0; c < 3; c++) {
        int col = c * 16 + ln;
        float as_ = (col < 40) ? as2[col] : 0.f;
        float ad_ = (col < 40) ? ad2[col] : 0.f;
#pragma unroll
        for (int reg = 0; reg < 4; reg++) {
            ps[reg] = fmaf(acc[c][reg], as_, ps[reg]);
            pd[reg] = fmaf(acc[c][reg], ad_, pd[reg]);
        }
    }
#pragma unroll
    for (int reg = 0; reg < 4; reg++) {
#pragma unroll
        for (int off = 1; off < 16; off <<= 1) {
            ps[reg] += __shfl_xor(ps[reg], off);
            pd[reg] += __shfl_xor(pd[reg], off);
        }
        int rg = row0 + w * 16 + q * 4 + reg;
        if (rg < N) {
            if (ln == 0) aS2[rg] = ps[reg] * LOG2E;
            if (ln == 1) aD2[rg] = pd[reg] * LOG2E;
        }
    }
}

// ---------------- fused message + softmax denominator, layer 1 ----------------
// 1 node/wave, 2 waves/block (fine-grain retirement for degree imbalance).
// 4 edge-slots of 16 lanes; each lane covers 8 channels (dwordx4 gather = one
// 256 B Af row per slot). First 64 neighbor ids bulk-loaded and served via
// ds_bpermute. Invalid slots clamp to row 0 (hot line) with w=0.
__global__ __launch_bounds__(128) void k_msg1(const int* __restrict__ offsets,
                                              const int* __restrict__ csr_src,
                                              const float* __restrict__ aS,
                                              const float* __restrict__ aD,
                                              const f16* __restrict__ Af,
                                              const float* __restrict__ b1,
                                              f16* __restrict__ Hf, int N) {
    const int lane = threadIdx.x & 63;
    const int n = blockIdx.x * 2 + (threadIdx.x >> 6);
    const bool node_ok = (n < N);
    const int g = lane >> 4;        // edge slot 0..3
    const int p = lane & 15;        // channel group: ch = p*8 .. p*8+7
    const int h = p >> 2;           // head 0..3

    int b = 0, e = 0;
    float adh = 0.f;
    if (node_ok) {
        b = offsets[n];
        e = offsets[n + 1];
        adh = aD[n * 4 + h];
    }

    float acc[8];
#pragma unroll
    for (int k = 0; k < 8; k++) acc[k] = 0.f;
    float wsum = 0.f;

    // self edge: all lanes load row n (broadcast); only slot 0 contributes.
    if (node_ok) {
        float xs = aS[n * 4 + h] + adh;
        float ws = __builtin_amdgcn_exp2f(fmaxf(xs, NEG_SLOPE * xs));
        if (g != 0) ws = 0.f;
        const f16x8 hv = *(const f16x8*)(Af + (size_t)n * 128 + p * 8);
#pragma unroll
        for (int k = 0; k < 8; k++) acc[k] = fmaf(ws, (float)hv[k], acc[k]);
        wsum = ws;
    }

    // preload up to 64 neighbor ids (one per lane)
    int sreg = 0;
    if (node_ok && e > b) {
        int idx = b + lane;
        if (idx >= e) idx = e - 1;
        sreg = csr_src[idx];
    }

    int i = b;
    // main loop: first 64 edges served from registers via bpermute
#pragma unroll 4
    for (; i < e && (i - b) + 4 <= 64; i += 4) {
        int j = i + g;
        bool valid = (j < e);
        int s = __builtin_amdgcn_ds_bpermute((j - b) << 2, sreg);
        if (!valid) s = 0;                               // hot row 0, w=0
        float sv = aS[s * 4 + h];
        const f16x8 hv = *(const f16x8*)(Af + (size_t)s * 128 + p * 8);
        float x = sv + adh;
        float wgt = __builtin_amdgcn_exp2f(fmaxf(x, NEG_SLOPE * x));
        if (!valid) wgt = 0.f;
#pragma unroll
        for (int k = 0; k < 8; k++) acc[k] = fmaf(wgt, (float)hv[k], acc[k]);
        wsum += wgt;
    }
    // residual (deg > 64): direct csr loads
    for (; i < e; i += 4) {
        int j = i + g;
        bool valid = (j < e);
        int jc = valid ? j : (e - 1);
        int s = csr_src[jc];
        if (!valid) s = 0;
        float sv = aS[s * 4 + h];
        const f16x8 hv = *(const f16x8*)(Af + (size_t)s * 128 + p * 8);
        float x = sv + adh;
        float wgt = __builtin_amdgcn_exp2f(fmaxf(x, NEG_SLOPE * x));
        if (!valid) wgt = 0.f;
#pragma unroll
        for (int k = 0; k < 8; k++) acc[k] = fmaf(wgt, (float)hv[k], acc[k]);
        wsum += wgt;
    }

    // reduce across the 4 edge slots (stride-16 lanes)
#pragma unroll
    for (int k = 0; k < 8; k++) {
        acc[k] += __shfl_xor(acc[k], 16);
        acc[k] += __shfl_xor(acc[k], 32);
    }
    wsum += __shfl_xor(wsum, 16);
    wsum += __shfl_xor(wsum, 32);

    if (node_ok && g == 0) {
        float inv = __builtin_amdgcn_rcpf(wsum);
        const float4* bb = (const float4*)(b1 + p * 8);
        float4 b0 = bb[0], b4 = bb[1];
        float bv[8] = {b0.x, b0.y, b0.z, b0.w, b4.x, b4.y, b4.z, b4.w};
        union { f16 h8[8]; uint4 u; } o;
#pragma unroll
        for (int k = 0; k < 8; k++) {
            float v = fmaf(acc[k], inv, bv[k]);
            o.h8[k] = (f16)fmaxf(v, 0.f);
        }
        *(uint4*)(Hf + (size_t)n * 128 + p * 8) = o.u;
    }
}

// ---------------- fused message + softmax denominator, layer 2 ----------------
// 1 node/wave, 2 waves/block. 12 edge-slots of 5 lanes; each lane covers 8 of
// 40 channels. X2f rows are PADDED to 64 f16 = one aligned 128B line per edge.
// Non-pow2 slot reduction via small LDS epilogue (no early returns).
__global__ __launch_bounds__(128) void k_msg2(const int* __restrict__ offsets,
                                              const int* __restrict__ csr_src,
                                              const float* __restrict__ aS,
                                              const float* __restrict__ aD,
                                              const f16* __restrict__ X2f,
                                              const float* __restrict__ b2,
                                              float* __restrict__ OUT, int N) {
    __shared__ float red[2][60][9];
    const int lane = threadIdx.x & 63;
    const int wv = threadIdx.x >> 6;
    const int n = blockIdx.x * 2 + wv;
    const bool node_ok = (n < N);
    const int g = lane / 5;          // edge slot 0..11 (lanes 60-63 inactive)
    const int p = lane % 5;          // channel group: ch = p*8 .. p*8+7
    const bool lane_ok = (g < 12);

    int b = 0, e = 0;
    float adh = 0.f;
    if (node_ok) {
        b = offsets[n];
        e = offsets[n + 1];
        adh = aD[n];
    }

    float acc[8];
#pragma unroll
    for (int k = 0; k < 8; k++) acc[k] = 0.f;
    float wsum = 0.f;

    // self edge (slot 0 contributes)
    if (node_ok) {
        float xs = aS[n] + adh;
        float ws = __builtin_amdgcn_exp2f(fmaxf(xs, NEG_SLOPE * xs));
        if (!(lane_ok && g == 0)) ws = 0.f;
        const f16x8 hv = *(const f16x8*)(X2f + (size_t)n * 64 + p * 8);
#pragma unroll
        for (int k = 0; k < 8; k++) acc[k] = fmaf(ws, (float)hv[k], acc[k]);
        wsum = ws;
    }

    int sreg = 0;
    if (node_ok && e > b) {
        int idx = b + lane;
        if (idx >= e) idx = e - 1;
        sreg = csr_src[idx];
    }

    int i = b;
    for (; i < e && (i - b) + 12 <= 64; i += 12) {
        int j = i + g;
        bool valid = lane_ok && (j < e);
        int s = __builtin_amdgcn_ds_bpermute(((j - b) & 63) << 2, sreg);
        if (!valid) s = 0;
        float sv = aS[s];
        const f16x8 hv = *(const f16x8*)(X2f + (size_t)s * 64 + p * 8);
        float x = sv + adh;
        float wgt = __builtin_amdgcn_exp2f(fmaxf(x, NEG_SLOPE * x));
        if (!valid) wgt = 0.f;
#pragma unroll
        for (int k = 0; k < 8; k++) acc[k] = fmaf(wgt, (float)hv[k], acc[k]);
        wsum += wgt;
    }
    for (; i < e; i += 12) {
        int j = i + g;
        bool valid = lane_ok && (j < e);
        int jc = (j < e) ? j : (e - 1);
        int s = csr_src[jc];
        if (!valid) s = 0;
        float sv = aS[s];
        const f16x8 hv = *(const f16x8*)(X2f + (size_t)s * 64 + p * 8);
        float x = sv + adh;
        float wgt = __builtin_amdgcn_exp2f(fmaxf(x, NEG_SLOPE * x));
        if (!valid) wgt = 0.f;
#pragma unroll
        for (int k = 0; k < 8; k++) acc[k] = fmaf(wgt, (float)hv[k], acc[k]);
        wsum += wgt;
    }

    if (lane_ok) {
#pragma unroll
        for (int k = 0; k < 8; k++) red[wv][lane][k] = acc[k];
        red[wv][lane][8] = wsum;
    }
    __syncthreads();

    if (node_ok && lane < 40) {
        int pp = lane >> 3, kk = lane & 7;
        float s_ = 0.f, ws_ = 0.f;
#pragma unroll
        for (int gg = 0; gg < 12; gg++) {
            s_  += red[wv][gg * 5 + pp][kk];
            ws_ += red[wv][gg * 5][8];
        }
        float inv = __builtin_amdgcn_rcpf(ws_);
        OUT[(size_t)n * 40 + lane] = fmaf(s_, inv, b2[lane]);
    }
}

extern "C" void kernel_launch(void* const* d_in, const int* in_sizes, int n_in,
                              void* d_out, int out_size, void* d_ws, size_t ws_size,
                              hipStream_t stream) {
    const float* x   = (const float*)d_in[0];
    const void*  ei  = d_in[1];
    const float* W1  = (const float*)d_in[2];
    const float* as1 = (const float*)d_in[3];
    const float* ad1 = (const float*)d_in[4];
    const float* b1  = (const float*)d_in[5];
    const float* W2  = (const float*)d_in[6];
    const float* as2 = (const float*)d_in[7];
    const float* ad2 = (const float*)d_in[8];
    const float* b2  = (const float*)d_in[9];
    float* out = (float*)d_out;

    const int N = in_sizes[0] / 128;
    const int E = in_sizes[1] / 2;

    // workspace layout — all 16B-aligned
    char* w = (char*)d_ws;
    auto alloc = [&](size_t bytes) {
        char* p = w;
        w += (bytes + 15) & ~(size_t)15;
        return p;
    };
    int* flag      = (int*)alloc(16);
    int* offsets   = (int*)alloc((size_t)(N + 1) * 4);
    int* deg       = (int*)alloc((size_t)N * 4);
    int* deg_part  = (int*)alloc((size_t)N * 8 * 4);   // [8][N] sharded histogram
    int* rank      = (int*)alloc((size_t)E * 4);
    int* csr_src   = (int*)alloc((size_t)E * 4);
    int* blksum    = (int*)alloc(64 * 4);
    int* blkoff    = (int*)alloc(64 * 4);
    float* aS1     = (float*)alloc((size_t)N * 4 * 4);
    float* aD1     = (float*)alloc((size_t)N * 4 * 4);
    float* aS2     = (float*)alloc((size_t)N * 4);
    float* aD2     = (float*)alloc((size_t)N * 4);
    f16* W1t       = (f16*)alloc(128 * 128 * 2);
    f16* W2t       = (f16*)alloc(48 * 128 * 2);
    f16* Af        = (f16*)alloc((size_t)N * 128 * 2);
    f16* X2f       = (f16*)alloc((size_t)N * 64 * 2);  // padded rows (128B lines)
    f16* Hf        = (f16*)alloc((size_t)N * 128 * 2);

    k_detect<<<1, 256, 0, stream>>>((const int*)ei, 1024, flag);
    k_prep<<<88, 256, 0, stream>>>(W1, W2, W1t, W2t);

    // CSR build (XCD-sharded; shared by both layers)
    hipMemsetAsync(deg_part, 0, (size_t)N * 8 * 4, stream);
    k_degree<<<(E + 255) / 256, 256, 0, stream>>>(ei, flag, deg_part, rank, N, E);
    k_sumdeg<<<(N + 255) / 256, 256, 0, stream>>>(deg_part, deg, N);
    const int G = (N + 4095) / 4096;
    k_scan_blk<<<G, 1024, 0, stream>>>(deg, offsets, blksum, N);
    k_scan_top<<<1, 64, 0, stream>>>(blksum, blkoff, G);
    k_scan_add<<<(N + 255) / 256, 256, 0, stream>>>(offsets, blkoff, N);
    k_scatter<<<(E + 255) / 256, 256, 0, stream>>>(ei, flag, offsets, deg_part, rank,
                                                   csr_src, N, E);

    // layer 1 (attn fused into gemm)
    const int gb = (N + 63) / 64;
    k_gemm1<<<gb, 256, 0, stream>>>(x, W1t, as1, ad1, Af, aS1, aD1, N);
    k_msg1<<<(N + 1) / 2, 128, 0, stream>>>(offsets, csr_src, aS1, aD1, Af, b1, Hf, N);

    // layer 2 (attn fused into gemm)
    k_gemm2<<<gb, 256, 0, stream>>>(Hf, W2t, as2, ad2, X2f, aS2, aD2, N);
    k_msg2<<<(N + 1) / 2, 128, 0, stream>>>(offsets, csr_src, aS2, aD2, X2f, b2, out, N);
}